// Round 8
// baseline (287.242 us; speedup 1.0000x reference)
//
#include <hip/hip_runtime.h>

typedef unsigned short u16;
typedef float f32x4 __attribute__((ext_vector_type(4)));
typedef short short8 __attribute__((ext_vector_type(8)));

#define S_LEN 2049
#define SPAD  2112      // padded per-batch row count (multiple of 64)
#define MP    4224      // 2 * SPAD padded token rows
#define MT16  264       // MP / 16
#define KSPLIT 11

__device__ __forceinline__ float b2f(u16 u){
  unsigned int i = ((unsigned int)u) << 16; float f; __builtin_memcpy(&f, &i, 4); return f;
}
__device__ __forceinline__ u16 f2b(float f){
  unsigned int i; __builtin_memcpy(&i, &f, 4);
  unsigned int r = i + 0x7FFFu + ((i >> 16) & 1u);
  return (u16)(r >> 16);
}
__device__ __forceinline__ u16 f2b_fast(float f){
  unsigned int i; __builtin_memcpy(&i, &f, 4);
  return (u16)((i + 0x8000u) >> 16);
}
#if __has_builtin(__builtin_amdgcn_exp2f)
#define EXP2F(x) __builtin_amdgcn_exp2f(x)
#else
#define EXP2F(x) exp2f(x)
#endif

// ---------------- canonical bf16 input region offsets (elements) -------------------
enum {
  OFF_X = 0,            OFF_EW = 262144,  OFF_EB = 270336,  OFF_POS = 270464,
  OFF_CLS = 794880,     OFF_IPW = 795008, OFF_IPB = 942464, OFF_OW = 943616,
  OFF_OB = 992768,      OFF_L1S = 993152, OFF_L1B = 993536, OFF_L2S = 993920,
  OFF_L2B = 994304,     OFF_F1W = 994688, OFF_F1B = 1191296, OFF_F2W = 1192832,
  OFF_F2B = 1389440,    OFF_HLS = 1389824, OFF_HLB = 1389952, OFF_HW = 1390080,
  OFF_HB = 1390208,     OFF_END = 1390209, CANON_PAD = 1390216
};

struct CArgs { const void* s[21]; };

// init: fp32->bf16 convert of all inputs + h CLS rows + zero h pad rows
__global__ __launch_bounds__(256) void init_kernel(
    CArgs a, u16* __restrict__ dst, float* __restrict__ h)
{
  const int offs[22] = {OFF_X,OFF_EW,OFF_EB,OFF_POS,OFF_CLS,OFF_IPW,OFF_IPB,OFF_OW,OFF_OB,
    OFF_L1S,OFF_L1B,OFF_L2S,OFF_L2B,OFF_F1W,OFF_F1B,OFF_F2W,OFF_F2B,OFF_HLS,OFF_HLB,
    OFF_HW,OFF_HB,OFF_END};
  int tid = blockIdx.x * 256 + threadIdx.x;
  if (tid < 256){
    int d = tid & 127, b = tid >> 7;
    h[(size_t)b * SPAD * 128 + d] =
        ((const float*)a.s[4])[d] + ((const float*)a.s[3])[d];
  }
  if (tid < 2 * 63 * 128){
    int b = tid / 8064, r = (tid % 8064) / 128, d = tid & 127;
    h[((size_t)b * SPAD + S_LEN + r) * 128 + d] = 0.f;
  }
  if (tid >= OFF_END) return;
  int lo = 0, hi = 21;
  while (hi - lo > 1){ int mid = (lo + hi) >> 1; if (tid >= offs[mid]) lo = mid; else hi = mid; }
  dst[tid] = f2b(((const float*)a.s[lo])[tid - offs[lo]]);
}

// ---------------- embedding as MFMA GEMM: h[b][s] = x@ew.T + eb + pos --------------
__global__ __launch_bounds__(256) void embed_kernel(const u16* __restrict__ cw, float* __restrict__ h)
{
  int lane = threadIdx.x & 63;
  int wave = blockIdx.x * 4 + (threadIdx.x >> 6);
  int mt = wave >> 3, nt = wave & 7;
  int mi = lane & 15, quad = lane >> 4;
  const u16* Ap = cw + OFF_X + (size_t)(mt * 16 + mi) * 64 + quad * 8;
  const u16* Wp = cw + OFF_EW + (size_t)(nt * 16 + mi) * 64 + quad * 8;
  f32x4 acc = {0.f, 0.f, 0.f, 0.f};
#pragma unroll
  for (int kc = 0; kc < 2; kc++){
    short8 av = *(const short8*)(Ap + kc * 32);
    short8 wv = *(const short8*)(Wp + kc * 32);
    acc = __builtin_amdgcn_mfma_f32_16x16x32_bf16(av, wv, acc, 0, 0, 0);
  }
  int n = nt * 16 + mi;
  float ebv = b2f(cw[OFF_EB + n]);
#pragma unroll
  for (int r = 0; r < 4; r++){
    int m = mt * 16 + quad * 4 + r;          // 0..4095 = b*2048 + (s-1)
    int b = m >> 11, s = (m & 2047) + 1;
    h[((size_t)b * SPAD + s) * 128 + n] =
        acc[r] + ebv + b2f(cw[OFF_POS + (size_t)s * 128 + n]);
  }
}

// LN helper: thread (tid>>5)=row, (tid&31)=c holds 4 row elems in x; writes bf16 Af.
__device__ __forceinline__ void ln_store(int tid, f32x4 x,
    const u16* __restrict__ g, const u16* __restrict__ be, u16* __restrict__ Af)
{
  int row = tid >> 5, c = tid & 31;
  float sm = x[0] + x[1] + x[2] + x[3];
  sm += __shfl_xor(sm,1,64); sm += __shfl_xor(sm,2,64); sm += __shfl_xor(sm,4,64);
  sm += __shfl_xor(sm,8,64); sm += __shfl_xor(sm,16,64);
  float mean = sm * (1.f/128.f);
  float d[4]; float vv = 0.f;
#pragma unroll
  for (int j = 0; j < 4; j++){ d[j] = x[j] - mean; vv += d[j]*d[j]; }
  vv += __shfl_xor(vv,1,64); vv += __shfl_xor(vv,2,64); vv += __shfl_xor(vv,4,64);
  vv += __shfl_xor(vv,8,64); vv += __shfl_xor(vv,16,64);
  float rstd = rsqrtf(vv * (1.f/128.f) + 1e-5f);
  ushort4 gv = *(const ushort4*)(g + c*4);
  ushort4 bv = *(const ushort4*)(be + c*4);
  ushort4 pk;
  pk.x = f2b(d[0]*rstd*b2f(gv.x) + b2f(bv.x));
  pk.y = f2b(d[1]*rstd*b2f(gv.y) + b2f(bv.y));
  pk.z = f2b(d[2]*rstd*b2f(gv.z) + b2f(bv.z));
  pk.w = f2b(d[3]*rstd*b2f(gv.w) + b2f(bv.w));
  *(ushort4*)&Af[row*136 + c*4] = pk;
}

// ---------------- fused C: [FF2+residual] + [LN1 + QKV] per 16-row tile ------------
// grid 264 x 512 threads (8 waves).
template<bool FF2, bool QKV>
__global__ __launch_bounds__(512, 2) void fused_c_kernel(
    float* __restrict__ h, const u16* __restrict__ f1,
    const u16* __restrict__ f2w, const u16* __restrict__ f2bias,
    const u16* __restrict__ g, const u16* __restrict__ be,
    const u16* __restrict__ ipw, const u16* __restrict__ ipb,
    u16* __restrict__ qkv)
{
  __shared__ float Ht[16 * 132];
  __shared__ u16 Af[16 * 136];
  int tid = threadIdx.x;
  int lane = tid & 63, w = tid >> 6;
  int mi = lane & 15, quad = lane >> 4;
  int m0 = blockIdx.x * 16;
  if (FF2){
    int n0 = w * 16;
    const u16* Ap = f1 + (size_t)(m0 + mi) * 512 + quad * 8;
    const u16* Wp = f2w + (size_t)(n0 + mi) * 512 + quad * 8;
    f32x4 acc = {0,0,0,0};
#pragma unroll
    for (int kc = 0; kc < 16; kc++){
      short8 a = *(const short8*)(Ap + kc * 32);
      short8 b = *(const short8*)(Wp + kc * 32);
      acc = __builtin_amdgcn_mfma_f32_16x16x32_bf16(a, b, acc, 0, 0, 0);
    }
    int n = n0 + mi;
    float bv = b2f(f2bias[n]);
#pragma unroll
    for (int r = 0; r < 4; r++){
      int m = m0 + quad * 4 + r;
      float val = h[(size_t)m * 128 + n] + acc[r] + bv;
      h[(size_t)m * 128 + n] = val;
      if (QKV) Ht[(quad * 4 + r) * 132 + n] = val;
    }
    if (QKV) __syncthreads();
  }
  if (QKV){
    // LN phase: 512 thr = 16 rows x 32 groups of 4 cols; LN computed ONCE per row
    {
      int row = tid >> 5, c = tid & 31;
      f32x4 x;
      if (FF2) x = *(const f32x4*)&Ht[row * 132 + c * 4];
      else     x = *(const f32x4*)(h + (size_t)(m0 + row) * 128 + c * 4);
      ln_store(tid, x, g, be, Af);
    }
    __syncthreads();
    // QKV GEMM: N=384 -> 24 n-tiles of 16, 3 per wave; A-frags from LDS once
    short8 af[4];
#pragma unroll
    for (int kc = 0; kc < 4; kc++)
      af[kc] = *(const short8*)&Af[mi * 136 + kc * 32 + quad * 8];
#pragma unroll
    for (int t = 0; t < 3; t++){
      int n0 = (w * 3 + t) * 16;
      const u16* Wp = ipw + (size_t)(n0 + mi) * 128 + quad * 8;
      f32x4 acc = {0,0,0,0};
#pragma unroll
      for (int kc = 0; kc < 4; kc++){
        short8 wv = *(const short8*)(Wp + kc * 32);
        acc = __builtin_amdgcn_mfma_f32_16x16x32_bf16(af[kc], wv, acc, 0, 0, 0);
      }
      int n = n0 + mi;
      float bv = b2f(ipb[n]);
      int which = n >> 7, d = n & 127, hd = d >> 5, dh = d & 31;
#pragma unroll
      for (int r = 0; r < 4; r++){
        int m = m0 + quad * 4 + r;
        int b_ = (m >= SPAD) ? 1 : 0;
        int s  = m - b_ * SPAD;
        qkv[(size_t)(((which * 2 + b_) * 4 + hd) * SPAD + s) * 32 + dh] = f2b(acc[r] + bv);
      }
    }
  }
}

// ---------------- fused B: split-reduce + out-proj + residual + LN2 + FF1 ----------
// grid 264 x 512 threads.
__global__ __launch_bounds__(512, 2) void fused_b_kernel(
    const float* __restrict__ Opart, const float* __restrict__ Lpart,
    const u16* __restrict__ ow, const u16* __restrict__ ob,
    float* __restrict__ h,
    const u16* __restrict__ g, const u16* __restrict__ be,
    const u16* __restrict__ f1w, const u16* __restrict__ f1b,
    u16* __restrict__ f1)
{
  __shared__ float Ht[16 * 132];
  __shared__ u16 Af[16 * 136];
  int tid = threadIdx.x;
  int mt = blockIdx.x, m0 = mt * 16;
  int b = mt / 132, tl = mt % 132;
  int qt = tl >> 2, wq = tl & 3;
  // phase 1: reduce 11 splits -> bf16 attnout tile in Af
  {
    int r = tid >> 5, rem = tid & 31;
    int hd = rem >> 3, dh0 = (rem & 7) * 4;
    int q = wq * 16 + r;
    size_t hb = ((size_t)qt * 8 + (b * 4 + hd)) * KSPLIT;
    const float* Ob = Opart + hb * 2048 + q * 32 + dh0;
    f32x4 acc = {0,0,0,0};
    float ls = 0.f;
#pragma unroll
    for (int sp = 0; sp < KSPLIT; sp++){
      acc += *(const f32x4*)(Ob + (size_t)sp * 2048);
      ls  += Lpart[(hb + sp) * 64 + q];
    }
    float inv = 1.f / fmaxf(ls, 1e-30f);
    ushort4 pk;
    pk.x = f2b(acc[0]*inv); pk.y = f2b(acc[1]*inv);
    pk.z = f2b(acc[2]*inv); pk.w = f2b(acc[3]*inv);
    *(ushort4*)&Af[r * 136 + hd * 32 + dh0] = pk;
  }
  __syncthreads();
  int lane = tid & 63, w = tid >> 6;
  int mi = lane & 15, quad = lane >> 4;
  // phase 2: out-proj (N=128, 1 n-tile per wave) + residual -> h global + Ht
  {
    short8 af[4];
#pragma unroll
    for (int kc = 0; kc < 4; kc++)
      af[kc] = *(const short8*)&Af[mi * 136 + kc * 32 + quad * 8];
    int n0 = w * 16;
    const u16* Wp = ow + (size_t)(n0 + mi) * 128 + quad * 8;
    f32x4 acc = {0,0,0,0};
#pragma unroll
    for (int kc = 0; kc < 4; kc++){
      short8 wv = *(const short8*)(Wp + kc * 32);
      acc = __builtin_amdgcn_mfma_f32_16x16x32_bf16(af[kc], wv, acc, 0, 0, 0);
    }
    int n = n0 + mi;
    float bv = b2f(ob[n]);
#pragma unroll
    for (int r = 0; r < 4; r++){
      int m = m0 + quad * 4 + r;
      float val = h[(size_t)m * 128 + n] + acc[r] + bv;
      h[(size_t)m * 128 + n] = val;
      Ht[(quad * 4 + r) * 132 + n] = val;
    }
  }
  __syncthreads();
  // phase 3: LN2 from Ht -> Af (overwrite)
  {
    int row = tid >> 5, c = tid & 31;
    f32x4 x = *(const f32x4*)&Ht[row * 132 + c * 4];
    ln_store(tid, x, g, be, Af);
  }
  __syncthreads();
  // phase 4: FF1 (N=512 -> 32 n-tiles, 4 per wave), relu -> f1 bf16
  {
    short8 af[4];
#pragma unroll
    for (int kc = 0; kc < 4; kc++)
      af[kc] = *(const short8*)&Af[mi * 136 + kc * 32 + quad * 8];
#pragma unroll
    for (int t = 0; t < 4; t++){
      int n0 = (w * 4 + t) * 16;
      const u16* Wp = f1w + (size_t)(n0 + mi) * 128 + quad * 8;
      f32x4 acc = {0,0,0,0};
#pragma unroll
      for (int kc = 0; kc < 4; kc++){
        short8 wv = *(const short8*)(Wp + kc * 32);
        acc = __builtin_amdgcn_mfma_f32_16x16x32_bf16(af[kc], wv, acc, 0, 0, 0);
      }
      int n = n0 + mi;
      float bv = b2f(f1b[n]);
#pragma unroll
      for (int r = 0; r < 4; r++){
        int m = m0 + quad * 4 + r;
        float val = acc[r] + bv;
        f1[(size_t)m * 512 + n] = f2b(val > 0.f ? val : 0.f);
      }
    }
  }
}

// ---------------- split-K flash attention, software-pipelined, KSPLIT=11 ----------
__global__ __launch_bounds__(256, 4) void attn_kernel(
    const u16* __restrict__ qkv, float* __restrict__ Opart, float* __restrict__ Lpart)
{
  __shared__ u16 Kl[64 * 40];
  __shared__ u16 Vt[32 * 72];
  __shared__ u16 Pl[4][16 * 72];
  int tid = threadIdx.x;
  int lane = tid & 63, w = tid >> 6;
  int qt = blockIdx.x, bh = blockIdx.y, split = blockIdx.z;
  const u16* Qb = qkv + (size_t)bh * SPAD * 32;
  const u16* Kb = qkv + (size_t)(8 + bh) * SPAD * 32;
  const u16* Vb = qkv + (size_t)(16 + bh) * SPAD * 32;
  int mi = lane & 15, quad = lane >> 4;
  int q0 = qt * 64 + w * 16;
  short8 qf = *(const short8*)(Qb + (size_t)(q0 + mi) * 32 + quad * 8);
  f32x4 o0 = {0,0,0,0}, o1 = {0,0,0,0};
  float lp[4] = {0.f, 0.f, 0.f, 0.f};
  int c0 = split * 3, c1 = c0 + 3;
  int kkey = tid >> 2, kdh = (tid & 3) * 8;
  int vdh = tid & 31, vgrp = tid >> 5;
  u16* Pw = Pl[w];
  short8 kreg = *(const short8*)(Kb + (size_t)(c0 * 64 + kkey) * 32 + kdh);
  ushort4 va, vb;
  {
    const u16* vp = Vb + (size_t)(c0 * 64 + vgrp * 4) * 32 + vdh;
    va.x = vp[0];    va.y = vp[32];   va.z = vp[64];   va.w = vp[96];
    vb.x = vp[1024]; vb.y = vp[1056]; vb.z = vp[1088]; vb.w = vp[1120];
  }
  for (int c = c0; c < c1; c++){
    __syncthreads();
    *(short8*)&Kl[kkey * 40 + kdh] = kreg;
    *(ushort4*)&Vt[vdh * 72 + vgrp * 4] = va;
    *(ushort4*)&Vt[vdh * 72 + (vgrp + 8) * 4] = vb;
    {
      int cn = (c + 1 < c1) ? c + 1 : c;
      kreg = *(const short8*)(Kb + (size_t)(cn * 64 + kkey) * 32 + kdh);
      const u16* vp = Vb + (size_t)(cn * 64 + vgrp * 4) * 32 + vdh;
      va.x = vp[0];    va.y = vp[32];   va.z = vp[64];   va.w = vp[96];
      vb.x = vp[1024]; vb.y = vp[1056]; vb.z = vp[1088]; vb.w = vp[1120];
    }
    __syncthreads();
    int kb = c * 64;
#pragma unroll
    for (int kt = 0; kt < 4; kt++){
      short8 kf = *(const short8*)&Kl[(kt * 16 + mi) * 40 + quad * 8];
      f32x4 z = {0,0,0,0};
      f32x4 s = __builtin_amdgcn_mfma_f32_16x16x32_bf16(qf, kf, z, 0, 0, 0);
      bool val = (kb + kt * 16 + mi) < S_LEN;
#pragma unroll
      for (int r = 0; r < 4; r++){
        float p = val ? EXP2F(s[r] * 0.25503486f) : 0.f;
        lp[r] += p;
        Pw[(quad * 4 + r) * 72 + kt * 16 + mi] = f2b_fast(p);
      }
    }
    short8 pf0 = *(const short8*)&Pw[mi * 72 + quad * 8];
    short8 pf1 = *(const short8*)&Pw[mi * 72 + 32 + quad * 8];
    short8 wa0 = *(const short8*)&Vt[mi * 72 + quad * 8];
    short8 wa1 = *(const short8*)&Vt[mi * 72 + 32 + quad * 8];
    short8 wb0 = *(const short8*)&Vt[(16 + mi) * 72 + quad * 8];
    short8 wb1 = *(const short8*)&Vt[(16 + mi) * 72 + 32 + quad * 8];
    o0 = __builtin_amdgcn_mfma_f32_16x16x32_bf16(pf0, wa0, o0, 0, 0, 0);
    o0 = __builtin_amdgcn_mfma_f32_16x16x32_bf16(pf1, wa1, o0, 0, 0, 0);
    o1 = __builtin_amdgcn_mfma_f32_16x16x32_bf16(pf0, wb0, o1, 0, 0, 0);
    o1 = __builtin_amdgcn_mfma_f32_16x16x32_bf16(pf1, wb1, o1, 0, 0, 0);
  }
#pragma unroll
  for (int r = 0; r < 4; r++){
    lp[r] += __shfl_xor(lp[r], 1, 64); lp[r] += __shfl_xor(lp[r], 2, 64);
    lp[r] += __shfl_xor(lp[r], 4, 64); lp[r] += __shfl_xor(lp[r], 8, 64);
  }
  size_t pb = ((size_t)qt * 8 + bh) * KSPLIT + split;
  float* Ob = Opart + pb * 2048 + (size_t)w * 16 * 32;
#pragma unroll
  for (int r = 0; r < 4; r++){
    Ob[(quad * 4 + r) * 32 + mi]      = o0[r];
    Ob[(quad * 4 + r) * 32 + 16 + mi] = o1[r];
  }
  if (mi == 0){
#pragma unroll
    for (int r = 0; r < 4; r++)
      Lpart[pb * 64 + w * 16 + quad * 4 + r] = lp[r];
  }
}

// ---------------- head: single wave, shfl-only -------------------------------------
__global__ __launch_bounds__(64) void head_kernel(
    const float* __restrict__ h, const u16* __restrict__ cw, float* __restrict__ out)
{
  int lane = threadIdx.x;
  for (int b = 0; b < 2; b++){
    float e0 = h[(size_t)b * SPAD * 128 + lane];
    float e1 = h[(size_t)b * SPAD * 128 + 64 + lane];
    float sm = e0 + e1;
    sm += __shfl_xor(sm,1,64); sm += __shfl_xor(sm,2,64); sm += __shfl_xor(sm,4,64);
    sm += __shfl_xor(sm,8,64); sm += __shfl_xor(sm,16,64); sm += __shfl_xor(sm,32,64);
    float mean = sm * (1.f/128.f);
    float d0 = e0 - mean, d1 = e1 - mean;
    float vv = d0*d0 + d1*d1;
    vv += __shfl_xor(vv,1,64); vv += __shfl_xor(vv,2,64); vv += __shfl_xor(vv,4,64);
    vv += __shfl_xor(vv,8,64); vv += __shfl_xor(vv,16,64); vv += __shfl_xor(vv,32,64);
    float rstd = rsqrtf(vv * (1.f/128.f) + 1e-5f);
    float v0 = d0 * rstd * b2f(cw[OFF_HLS + lane])      + b2f(cw[OFF_HLB + lane]);
    float v1 = d1 * rstd * b2f(cw[OFF_HLS + 64 + lane]) + b2f(cw[OFF_HLB + 64 + lane]);
    float dot = v0 * b2f(cw[OFF_HW + lane]) + v1 * b2f(cw[OFF_HW + 64 + lane]);
    dot += __shfl_xor(dot,1,64); dot += __shfl_xor(dot,2,64); dot += __shfl_xor(dot,4,64);
    dot += __shfl_xor(dot,8,64); dot += __shfl_xor(dot,16,64); dot += __shfl_xor(dot,32,64);
    if (lane == 0) out[b] = dot + b2f(cw[OFF_HB]);
  }
}

extern "C" void kernel_launch(void* const* d_in, const int* in_sizes, int n_in,
                              void* d_out, int out_size, void* d_ws, size_t ws_size,
                              hipStream_t stream)
{
  char* ws = (char*)d_ws;
  u16* cw     = (u16*)ws;    ws += (size_t)CANON_PAD * 2;
  float* h    = (float*)ws;  ws += (size_t)MP * 128 * 4;
  u16* qkv    = (u16*)ws;    ws += (size_t)24 * SPAD * 32 * 2;
  u16* f1     = (u16*)ws;    ws += (size_t)MP * 512 * 2;
  float* Opart= (float*)ws;  ws += (size_t)33 * 8 * KSPLIT * 2048 * 4;
  float* Lpart= (float*)ws;  ws += (size_t)33 * 8 * KSPLIT * 64 * 4;

  CArgs ca;
  for (int i = 0; i < 21; i++) ca.s[i] = d_in[i];

  init_kernel<<<dim3((OFF_END + 255) / 256), dim3(256), 0, stream>>>(ca, cw, h);
  embed_kernel<<<dim3(512), dim3(256), 0, stream>>>(cw, h);
  // layer-0 QKV (no FF2)
  fused_c_kernel<false, true><<<dim3(MT16), dim3(512), 0, stream>>>(
      h, nullptr, nullptr, nullptr,
      cw + OFF_L1S, cw + OFF_L1B, cw + OFF_IPW, cw + OFF_IPB, qkv);
  for (int l = 0; l < 3; l++){
    attn_kernel<<<dim3(33, 8, KSPLIT), dim3(256), 0, stream>>>(qkv, Opart, Lpart);
    fused_b_kernel<<<dim3(MT16), dim3(512), 0, stream>>>(
        Opart, Lpart, cw + OFF_OW + (size_t)l * 128 * 128, cw + OFF_OB + l * 128, h,
        cw + OFF_L2S + l * 128, cw + OFF_L2B + l * 128,
        cw + OFF_F1W + (size_t)l * 512 * 128, cw + OFF_F1B + l * 512, f1);
    if (l < 2){
      fused_c_kernel<true, true><<<dim3(MT16), dim3(512), 0, stream>>>(
          h, f1, cw + OFF_F2W + (size_t)l * 128 * 512, cw + OFF_F2B + l * 128,
          cw + OFF_L1S + (l+1) * 128, cw + OFF_L1B + (l+1) * 128,
          cw + OFF_IPW + (size_t)(l+1) * 384 * 128, cw + OFF_IPB + (l+1) * 384, qkv);
    } else {
      fused_c_kernel<true, false><<<dim3(MT16), dim3(512), 0, stream>>>(
          h, f1, cw + OFF_F2W + (size_t)l * 128 * 512, cw + OFF_F2B + l * 128,
          nullptr, nullptr, nullptr, nullptr, nullptr);
    }
  }
  head_kernel<<<dim3(1), dim3(64), 0, stream>>>(h, cw, (float*)d_out);
}

// Round 9
// 277.335 us; speedup vs baseline: 1.0357x; 1.0357x over previous
//
#include <hip/hip_runtime.h>

typedef unsigned short u16;
typedef float f32x4 __attribute__((ext_vector_type(4)));
typedef short short8 __attribute__((ext_vector_type(8)));

#define S_LEN 2049
#define SPAD  2112      // padded per-batch row count (multiple of 64)
#define MP    4224      // 2 * SPAD padded token rows
#define MT    264       // MP / 16
#define MT32  132       // MP / 32
#define KSPLIT 11

__device__ __forceinline__ float b2f(u16 u){
  unsigned int i = ((unsigned int)u) << 16; float f; __builtin_memcpy(&f, &i, 4); return f;
}
__device__ __forceinline__ u16 f2b(float f){
  unsigned int i; __builtin_memcpy(&i, &f, 4);
  unsigned int r = i + 0x7FFFu + ((i >> 16) & 1u);
  return (u16)(r >> 16);
}
__device__ __forceinline__ u16 f2b_fast(float f){  // round-to-nearest (no tie-even)
  unsigned int i; __builtin_memcpy(&i, &f, 4);
  return (u16)((i + 0x8000u) >> 16);
}
#if __has_builtin(__builtin_amdgcn_exp2f)
#define EXP2F(x) __builtin_amdgcn_exp2f(x)
#else
#define EXP2F(x) exp2f(x)
#endif

// ---------------- canonical bf16 input region offsets (elements) -------------------
enum {
  OFF_X = 0,            OFF_EW = 262144,  OFF_EB = 270336,  OFF_POS = 270464,
  OFF_CLS = 794880,     OFF_IPW = 795008, OFF_IPB = 942464, OFF_OW = 943616,
  OFF_OB = 992768,      OFF_L1S = 993152, OFF_L1B = 993536, OFF_L2S = 993920,
  OFF_L2B = 994304,     OFF_F1W = 994688, OFF_F1B = 1191296, OFF_F2W = 1192832,
  OFF_F2B = 1389440,    OFF_HLS = 1389824, OFF_HLB = 1389952, OFF_HW = 1390080,
  OFF_HB = 1390208,     OFF_END = 1390209, CANON_PAD = 1390216
};

struct CArgs { const void* s[21]; };

// init: fp32->bf16 convert of all inputs + h CLS rows + zero h pad rows
__global__ __launch_bounds__(256) void init_kernel(
    CArgs a, u16* __restrict__ dst, float* __restrict__ h)
{
  const int offs[22] = {OFF_X,OFF_EW,OFF_EB,OFF_POS,OFF_CLS,OFF_IPW,OFF_IPB,OFF_OW,OFF_OB,
    OFF_L1S,OFF_L1B,OFF_L2S,OFF_L2B,OFF_F1W,OFF_F1B,OFF_F2W,OFF_F2B,OFF_HLS,OFF_HLB,
    OFF_HW,OFF_HB,OFF_END};
  int tid = blockIdx.x * 256 + threadIdx.x;
  if (tid < 256){                    // CLS rows (fp32 sources)
    int d = tid & 127, b = tid >> 7;
    h[(size_t)b * SPAD * 128 + d] =
        ((const float*)a.s[4])[d] + ((const float*)a.s[3])[d];
  }
  if (tid < 2 * 63 * 128){           // zero h pad rows s in [2049,2112)
    int b = tid / 8064, r = (tid % 8064) / 128, d = tid & 127;
    h[((size_t)b * SPAD + S_LEN + r) * 128 + d] = 0.f;
  }
  if (tid >= OFF_END) return;
  int lo = 0, hi = 21;
  while (hi - lo > 1){ int mid = (lo + hi) >> 1; if (tid >= offs[mid]) lo = mid; else hi = mid; }
  dst[tid] = f2b(((const float*)a.s[lo])[tid - offs[lo]]);
}

// ---------------- embedding as MFMA GEMM: h[b][s] = x@ew.T + eb + pos --------------
__global__ __launch_bounds__(256) void embed_kernel(const u16* __restrict__ cw, float* __restrict__ h)
{
  int lane = threadIdx.x & 63;
  int wave = blockIdx.x * 4 + (threadIdx.x >> 6);
  int mt = wave >> 3, nt = wave & 7;
  int mi = lane & 15, quad = lane >> 4;
  const u16* Ap = cw + OFF_X + (size_t)(mt * 16 + mi) * 64 + quad * 8;
  const u16* Wp = cw + OFF_EW + (size_t)(nt * 16 + mi) * 64 + quad * 8;
  f32x4 acc = {0.f, 0.f, 0.f, 0.f};
#pragma unroll
  for (int kc = 0; kc < 2; kc++){
    short8 av = *(const short8*)(Ap + kc * 32);
    short8 wv = *(const short8*)(Wp + kc * 32);
    acc = __builtin_amdgcn_mfma_f32_16x16x32_bf16(av, wv, acc, 0, 0, 0);
  }
  int n = nt * 16 + mi;
  float ebv = b2f(cw[OFF_EB + n]);
#pragma unroll
  for (int r = 0; r < 4; r++){
    int m = mt * 16 + quad * 4 + r;          // 0..4095 = b*2048 + (s-1)
    int b = m >> 11, s = (m & 2047) + 1;
    h[((size_t)b * SPAD + s) * 128 + n] =
        acc[r] + ebv + b2f(cw[OFF_POS + (size_t)s * 128 + n]);
  }
}

// ---------------- LN-fused MFMA GEMM, 32x32 wave tiles -----------------------------
// MODE 0: scatter to qkv [which][b*H+h][SPAD][32]; MODE 2: relu -> bf16 out [m][N]
template<int N, int MODE>
__global__ __launch_bounds__(256) void lngemm_kernel(
    const float* __restrict__ h,
    const u16* __restrict__ g, const u16* __restrict__ be,
    const u16* __restrict__ W, const u16* __restrict__ bias, u16* __restrict__ out)
{
  constexpr int NT = N / 32;
  int lane = threadIdx.x & 63;
  int wave = blockIdx.x * 4 + (threadIdx.x >> 6);
  int mt = wave / NT, nt = wave - mt * NT;    // mt 0..131
  int mi = lane & 15, quad = lane >> 4;
  short8 af[2][4];
#pragma unroll
  for (int gi = 0; gi < 2; gi++){
    const float* hrow = h + (size_t)(mt * 32 + gi * 16 + mi) * 128 + quad * 8;
    float v[32];
    float sm = 0.f;
#pragma unroll
    for (int kc = 0; kc < 4; kc++){
      f32x4 x0 = *(const f32x4*)(hrow + kc * 32);
      f32x4 x1 = *(const f32x4*)(hrow + kc * 32 + 4);
#pragma unroll
      for (int j = 0; j < 4; j++){ v[kc*8+j] = x0[j]; v[kc*8+4+j] = x1[j]; }
      sm += x0[0]+x0[1]+x0[2]+x0[3]+x1[0]+x1[1]+x1[2]+x1[3];
    }
    sm += __shfl_xor(sm, 16, 64); sm += __shfl_xor(sm, 32, 64);
    float mean = sm * (1.f/128.f);
    float vv = 0.f;
#pragma unroll
    for (int j = 0; j < 32; j++){ float d = v[j] - mean; vv += d * d; }
    vv += __shfl_xor(vv, 16, 64); vv += __shfl_xor(vv, 32, 64);
    float rstd = rsqrtf(vv * (1.f/128.f) + 1e-5f);
#pragma unroll
    for (int kc = 0; kc < 4; kc++){
      short8 gs = *(const short8*)(g  + kc * 32 + quad * 8);
      short8 bs = *(const short8*)(be + kc * 32 + quad * 8);
#pragma unroll
      for (int j = 0; j < 8; j++)
        af[gi][kc][j] = (short)f2b((v[kc*8+j] - mean) * rstd * b2f((u16)gs[j]) + b2f((u16)bs[j]));
    }
  }
  const u16* W0 = W + (size_t)(nt * 32 + mi) * 128 + quad * 8;
  const u16* W1 = W0 + 16 * 128;
  f32x4 a00 = {0,0,0,0}, a01 = {0,0,0,0}, a10 = {0,0,0,0}, a11 = {0,0,0,0};
#pragma unroll
  for (int kc = 0; kc < 4; kc++){
    short8 w0 = *(const short8*)(W0 + kc * 32);
    short8 w1 = *(const short8*)(W1 + kc * 32);
    a00 = __builtin_amdgcn_mfma_f32_16x16x32_bf16(af[0][kc], w0, a00, 0, 0, 0);
    a01 = __builtin_amdgcn_mfma_f32_16x16x32_bf16(af[0][kc], w1, a01, 0, 0, 0);
    a10 = __builtin_amdgcn_mfma_f32_16x16x32_bf16(af[1][kc], w0, a10, 0, 0, 0);
    a11 = __builtin_amdgcn_mfma_f32_16x16x32_bf16(af[1][kc], w1, a11, 0, 0, 0);
  }
#pragma unroll
  for (int gi = 0; gi < 2; gi++){
#pragma unroll
    for (int wsel = 0; wsel < 2; wsel++){
      f32x4 acc = gi ? (wsel ? a11 : a10) : (wsel ? a01 : a00);
      int n = nt * 32 + wsel * 16 + mi;
      float bv = b2f(bias[n]);
#pragma unroll
      for (int r = 0; r < 4; r++){
        int m = mt * 32 + gi * 16 + quad * 4 + r;
        float val = acc[r] + bv;
        if (MODE == 0){
          int which = n >> 7, d = n & 127, hd = d >> 5, dh = d & 31;
          int b_ = (m >= SPAD) ? 1 : 0;
          int s  = m - b_ * SPAD;
          out[(size_t)(((which * 2 + b_) * 4 + hd) * SPAD + s) * 32 + dh] = f2b(val);
        } else {
          out[(size_t)m * N + n] = f2b(val > 0.f ? val : 0.f);
        }
      }
    }
  }
}

// ---------------- FF2: bf16 A GEMM 32x32 tiles, K=512, residual into fp32 h --------
__global__ __launch_bounds__(256) void gemm_res_kernel(
    const u16* __restrict__ A, const u16* __restrict__ W, const u16* __restrict__ bias,
    float* __restrict__ hres)
{
  int lane = threadIdx.x & 63;
  int wave = blockIdx.x * 4 + (threadIdx.x >> 6);
  int mt = wave >> 2, nt = wave & 3;           // 132 x 4 tiles
  int mi = lane & 15, quad = lane >> 4;
  const u16* A0 = A + (size_t)(mt * 32 + mi) * 512 + quad * 8;
  const u16* A1 = A0 + 16 * 512;
  const u16* W0 = W + (size_t)(nt * 32 + mi) * 512 + quad * 8;
  const u16* W1 = W0 + 16 * 512;
  f32x4 a00 = {0,0,0,0}, a01 = {0,0,0,0}, a10 = {0,0,0,0}, a11 = {0,0,0,0};
#pragma unroll
  for (int kc = 0; kc < 16; kc++){
    short8 x0 = *(const short8*)(A0 + kc * 32);
    short8 x1 = *(const short8*)(A1 + kc * 32);
    short8 w0 = *(const short8*)(W0 + kc * 32);
    short8 w1 = *(const short8*)(W1 + kc * 32);
    a00 = __builtin_amdgcn_mfma_f32_16x16x32_bf16(x0, w0, a00, 0, 0, 0);
    a01 = __builtin_amdgcn_mfma_f32_16x16x32_bf16(x0, w1, a01, 0, 0, 0);
    a10 = __builtin_amdgcn_mfma_f32_16x16x32_bf16(x1, w0, a10, 0, 0, 0);
    a11 = __builtin_amdgcn_mfma_f32_16x16x32_bf16(x1, w1, a11, 0, 0, 0);
  }
#pragma unroll
  for (int gi = 0; gi < 2; gi++){
#pragma unroll
    for (int wsel = 0; wsel < 2; wsel++){
      f32x4 acc = gi ? (wsel ? a11 : a10) : (wsel ? a01 : a00);
      int n = nt * 32 + wsel * 16 + mi;
      float bv = b2f(bias[n]);
#pragma unroll
      for (int r = 0; r < 4; r++){
        int m = mt * 32 + gi * 16 + quad * 4 + r;
        hres[(size_t)m * 128 + n] += acc[r] + bv;
      }
    }
  }
}

// ---------------- split-K flash attention, software-pipelined, bf16 partials -------
// grid (33, 8 bh, 11); block 256 (4 waves x 16 q rows). 3 chunks of 64 keys each.
__global__ __launch_bounds__(256) void attn_kernel(
    const u16* __restrict__ qkv, u16* __restrict__ Opart, float* __restrict__ Lpart)
{
  __shared__ u16 Kl[64 * 40];      // K chunk [key][dh], pitch 40
  __shared__ u16 Vt[32 * 72];      // V chunk transposed [dh][key], pitch 72
  __shared__ u16 Pl[4][16 * 72];   // per-wave P bounce [row][key], pitch 72
  int tid = threadIdx.x;
  int lane = tid & 63, w = tid >> 6;
  int qt = blockIdx.x, bh = blockIdx.y, split = blockIdx.z;
  const u16* Qb = qkv + (size_t)bh * SPAD * 32;
  const u16* Kb = qkv + (size_t)(8 + bh) * SPAD * 32;
  const u16* Vb = qkv + (size_t)(16 + bh) * SPAD * 32;
  int mi = lane & 15, quad = lane >> 4;
  int q0 = qt * 64 + w * 16;
  short8 qf = *(const short8*)(Qb + (size_t)(q0 + mi) * 32 + quad * 8);
  f32x4 o0 = {0,0,0,0}, o1 = {0,0,0,0};
  float lp[4] = {0.f, 0.f, 0.f, 0.f};
  int c0 = split * 3, c1 = c0 + 3;
  int kkey = tid >> 2, kdh = (tid & 3) * 8;
  int vdh = tid & 31, vgrp = tid >> 5;
  u16* Pw = Pl[w];
  short8 kreg = *(const short8*)(Kb + (size_t)(c0 * 64 + kkey) * 32 + kdh);
  ushort4 va, vb;
  {
    const u16* vp = Vb + (size_t)(c0 * 64 + vgrp * 4) * 32 + vdh;
    va.x = vp[0];    va.y = vp[32];   va.z = vp[64];   va.w = vp[96];
    vb.x = vp[1024]; vb.y = vp[1056]; vb.z = vp[1088]; vb.w = vp[1120];
  }
  for (int c = c0; c < c1; c++){
    __syncthreads();                    // prev chunk's LDS readers done
    *(short8*)&Kl[kkey * 40 + kdh] = kreg;
    *(ushort4*)&Vt[vdh * 72 + vgrp * 4] = va;
    *(ushort4*)&Vt[vdh * 72 + (vgrp + 8) * 4] = vb;
    {                                   // prefetch next chunk (clamped; overlaps compute)
      int cn = (c + 1 < c1) ? c + 1 : c;
      kreg = *(const short8*)(Kb + (size_t)(cn * 64 + kkey) * 32 + kdh);
      const u16* vp = Vb + (size_t)(cn * 64 + vgrp * 4) * 32 + vdh;
      va.x = vp[0];    va.y = vp[32];   va.z = vp[64];   va.w = vp[96];
      vb.x = vp[1024]; vb.y = vp[1056]; vb.z = vp[1088]; vb.w = vp[1120];
    }
    __syncthreads();                    // LDS ready
    int kb = c * 64;
#pragma unroll
    for (int kt = 0; kt < 4; kt++){
      short8 kf = *(const short8*)&Kl[(kt * 16 + mi) * 40 + quad * 8];
      f32x4 z = {0,0,0,0};
      f32x4 s = __builtin_amdgcn_mfma_f32_16x16x32_bf16(qf, kf, z, 0, 0, 0);
      bool val = (kb + kt * 16 + mi) < S_LEN;
#pragma unroll
      for (int r = 0; r < 4; r++){
        float p = val ? EXP2F(s[r] * 0.25503486f) : 0.f;   // scale/sqrt(32)*log2e
        lp[r] += p;
        Pw[(quad * 4 + r) * 72 + kt * 16 + mi] = f2b_fast(p);
      }
    }
    // P is wave-private: no block barrier needed before reading it back
    short8 pf0 = *(const short8*)&Pw[mi * 72 + quad * 8];
    short8 pf1 = *(const short8*)&Pw[mi * 72 + 32 + quad * 8];
    short8 wa0 = *(const short8*)&Vt[mi * 72 + quad * 8];
    short8 wa1 = *(const short8*)&Vt[mi * 72 + 32 + quad * 8];
    short8 wb0 = *(const short8*)&Vt[(16 + mi) * 72 + quad * 8];
    short8 wb1 = *(const short8*)&Vt[(16 + mi) * 72 + 32 + quad * 8];
    o0 = __builtin_amdgcn_mfma_f32_16x16x32_bf16(pf0, wa0, o0, 0, 0, 0);
    o0 = __builtin_amdgcn_mfma_f32_16x16x32_bf16(pf1, wa1, o0, 0, 0, 0);
    o1 = __builtin_amdgcn_mfma_f32_16x16x32_bf16(pf0, wb0, o1, 0, 0, 0);
    o1 = __builtin_amdgcn_mfma_f32_16x16x32_bf16(pf1, wb1, o1, 0, 0, 0);
  }
#pragma unroll
  for (int r = 0; r < 4; r++){
    lp[r] += __shfl_xor(lp[r], 1, 64); lp[r] += __shfl_xor(lp[r], 2, 64);
    lp[r] += __shfl_xor(lp[r], 4, 64); lp[r] += __shfl_xor(lp[r], 8, 64);
  }
  size_t pb = ((size_t)qt * 8 + bh) * KSPLIT + split;
  u16* Ob = Opart + pb * 2048 + (size_t)w * 16 * 32;
#pragma unroll
  for (int r = 0; r < 4; r++){        // bf16 partials (halve Opart traffic)
    Ob[(quad * 4 + r) * 32 + mi]      = f2b(o0[r]);
    Ob[(quad * 4 + r) * 32 + 16 + mi] = f2b(o1[r]);
  }
  if (mi == 0){
#pragma unroll
    for (int r = 0; r < 4; r++)
      Lpart[pb * 64 + w * 16 + quad * 4 + r] = lp[r];
  }
}

// ---------------- fused: split-reduce + normalize + out-proj + residual ------------
__global__ __launch_bounds__(512, 2) void redout_kernel(
    const u16* __restrict__ Opart, const float* __restrict__ Lpart,
    const u16* __restrict__ W, const u16* __restrict__ bias, float* __restrict__ hres)
{
  __shared__ u16 Al[16 * 136];     // reduced attn tile [r][hd*32+dh], pitch 136
  int tid = threadIdx.x;
  int mt = blockIdx.x;
  int b = mt / 132, tle = mt % 132;
  int qt = tle >> 2, w = tle & 3;
  {
    int hd = tid >> 7;               // 0..3
    int e  = (tid * 4) & 511;
    int r  = e >> 5, dh0 = e & 31;
    size_t hb = ((size_t)qt * 8 + (b * 4 + hd)) * KSPLIT;
    size_t base = hb * 2048 + w * 512 + r * 32 + dh0;
    f32x4 acc = {0,0,0,0};
    float ls = 0.f;
#pragma unroll
    for (int sp = 0; sp < KSPLIT; sp++){
      ushort4 pv = *(const ushort4*)(Opart + base + (size_t)sp * 2048);
      acc[0] += b2f(pv.x); acc[1] += b2f(pv.y); acc[2] += b2f(pv.z); acc[3] += b2f(pv.w);
      ls  += Lpart[(hb + sp) * 64 + w * 16 + r];
    }
    float inv = 1.f / fmaxf(ls, 1e-30f);
    ushort4 pk;
    pk.x = f2b(acc[0] * inv); pk.y = f2b(acc[1] * inv);
    pk.z = f2b(acc[2] * inv); pk.w = f2b(acc[3] * inv);
    *(ushort4*)&Al[r * 136 + hd * 32 + dh0] = pk;
  }
  __syncthreads();
  int lane = tid & 63, nt = tid >> 6;
  int mi = lane & 15, quad = lane >> 4;
  const u16* Wp = W + (size_t)(nt * 16 + mi) * 128 + quad * 8;
  f32x4 acc = {0.f, 0.f, 0.f, 0.f};
#pragma unroll
  for (int kc = 0; kc < 4; kc++){
    short8 af = *(const short8*)&Al[mi * 136 + kc * 32 + quad * 8];
    short8 wv = *(const short8*)(Wp + kc * 32);
    acc = __builtin_amdgcn_mfma_f32_16x16x32_bf16(af, wv, acc, 0, 0, 0);
  }
  int n = nt * 16 + mi;
  float bv = b2f(bias[n]);
#pragma unroll
  for (int r = 0; r < 4; r++){
    int m = mt * 16 + quad * 4 + r;
    hres[(size_t)m * 128 + n] += acc[r] + bv;
  }
}

// ---------------- head: single wave, shfl-only -------------------------------------
__global__ __launch_bounds__(64) void head_kernel(
    const float* __restrict__ h, const u16* __restrict__ cw, float* __restrict__ out)
{
  int lane = threadIdx.x;
  for (int b = 0; b < 2; b++){
    float e0 = h[(size_t)b * SPAD * 128 + lane];
    float e1 = h[(size_t)b * SPAD * 128 + 64 + lane];
    float sm = e0 + e1;
    sm += __shfl_xor(sm,1,64); sm += __shfl_xor(sm,2,64); sm += __shfl_xor(sm,4,64);
    sm += __shfl_xor(sm,8,64); sm += __shfl_xor(sm,16,64); sm += __shfl_xor(sm,32,64);
    float mean = sm * (1.f/128.f);
    float d0 = e0 - mean, d1 = e1 - mean;
    float vv = d0*d0 + d1*d1;
    vv += __shfl_xor(vv,1,64); vv += __shfl_xor(vv,2,64); vv += __shfl_xor(vv,4,64);
    vv += __shfl_xor(vv,8,64); vv += __shfl_xor(vv,16,64); vv += __shfl_xor(vv,32,64);
    float rstd = rsqrtf(vv * (1.f/128.f) + 1e-5f);
    float v0 = d0 * rstd * b2f(cw[OFF_HLS + lane])      + b2f(cw[OFF_HLB + lane]);
    float v1 = d1 * rstd * b2f(cw[OFF_HLS + 64 + lane]) + b2f(cw[OFF_HLB + 64 + lane]);
    float dot = v0 * b2f(cw[OFF_HW + lane]) + v1 * b2f(cw[OFF_HW + 64 + lane]);
    dot += __shfl_xor(dot,1,64); dot += __shfl_xor(dot,2,64); dot += __shfl_xor(dot,4,64);
    dot += __shfl_xor(dot,8,64); dot += __shfl_xor(dot,16,64); dot += __shfl_xor(dot,32,64);
    if (lane == 0) out[b] = dot + b2f(cw[OFF_HB]);
  }
}

extern "C" void kernel_launch(void* const* d_in, const int* in_sizes, int n_in,
                              void* d_out, int out_size, void* d_ws, size_t ws_size,
                              hipStream_t stream)
{
  char* ws = (char*)d_ws;
  u16* cw     = (u16*)ws;    ws += (size_t)CANON_PAD * 2;
  float* h    = (float*)ws;  ws += (size_t)MP * 128 * 4;
  u16* qkv    = (u16*)ws;    ws += (size_t)24 * SPAD * 32 * 2;
  u16* f1     = (u16*)ws;    ws += (size_t)MP * 512 * 2;
  u16* Opart  = (u16*)ws;    ws += (size_t)33 * 8 * KSPLIT * 2048 * 2;
  float* Lpart= (float*)ws;  ws += (size_t)33 * 8 * KSPLIT * 64 * 4;

  CArgs ca;
  for (int i = 0; i < 21; i++) ca.s[i] = d_in[i];

  init_kernel<<<dim3((OFF_END + 255) / 256), dim3(256), 0, stream>>>(ca, cw, h);
  embed_kernel<<<dim3(512), dim3(256), 0, stream>>>(cw, h);
  for (int l = 0; l < 3; l++){
    lngemm_kernel<384, 0><<<dim3(MT32 * 12 / 4), dim3(256), 0, stream>>>(
        h, cw + OFF_L1S + l * 128, cw + OFF_L1B + l * 128,
        cw + OFF_IPW + (size_t)l * 384 * 128, cw + OFF_IPB + l * 384, qkv);
    attn_kernel<<<dim3(33, 8, KSPLIT), dim3(256), 0, stream>>>(qkv, Opart, Lpart);
    redout_kernel<<<dim3(MT), dim3(512), 0, stream>>>(
        Opart, Lpart, cw + OFF_OW + (size_t)l * 128 * 128, cw + OFF_OB + l * 128, h);
    lngemm_kernel<512, 2><<<dim3(MT32 * 16 / 4), dim3(256), 0, stream>>>(
        h, cw + OFF_L2S + l * 128, cw + OFF_L2B + l * 128,
        cw + OFF_F1W + (size_t)l * 512 * 128, cw + OFF_F1B + l * 512, f1);
    gemm_res_kernel<<<dim3(MT32), dim3(256), 0, stream>>>(
        f1, cw + OFF_F2W + (size_t)l * 128 * 512, cw + OFF_F2B + l * 128, h);
  }
  head_kernel<<<dim3(1), dim3(64), 0, stream>>>(h, cw, (float*)d_out);
}